// Round 19
// baseline (162.641 us; speedup 1.0000x reference)
//
#include <hip/hip_runtime.h>
#include <hip/hip_bf16.h>
#include <math.h>

typedef __bf16 bf16_t;
typedef __bf16 bf16x4_t __attribute__((ext_vector_type(4)));
typedef __bf16 bf16x8 __attribute__((ext_vector_type(8)));
typedef float f32x4 __attribute__((ext_vector_type(4)));
typedef unsigned long long u64;

#define NB 1024
#define NN 75
#define KF 512
#define F1 256
#define HSTR 100
#define ASTR 100

// ---------------------------------------------------------------------------
// Kernel 0: W [512][256] fp32 -> Wt [256][512] bf16 (unchanged, passing)
// ---------------------------------------------------------------------------
__global__ __launch_bounds__(256) void wt_kernel(const float* __restrict__ W,
                                                 bf16_t* __restrict__ Wt) {
    __shared__ float tile[64][65];
    const int kb = blockIdx.x * 64;
    const int nb = blockIdx.y * 64;
    const int tc = threadIdx.x & 63;
    const int tr = threadIdx.x >> 6;
#pragma unroll
    for (int r = tr; r < 64; r += 4)
        tile[r][tc] = W[(size_t)(kb + r) * F1 + nb + tc];
    __syncthreads();
#pragma unroll
    for (int r = tr; r < 64; r += 4)
        Wt[(size_t)(nb + r) * KF + kb + tc] = (bf16_t)tile[tc][r];
}

// ---------------------------------------------------------------------------
// Kernel 1: h = X @ W -> out[...,256:512].  MAX-TLP variant.
// BM=32 -> 2400 blocks x 4 waves; LDS 32KB + VGPR<=128 (__launch_bounds__
// (256,4)) -> 4 blocks/CU = 16 waves/CU (2x all prior variants).
// Staging: wave-contiguous 2KB bursts, r17-verified XOR chunk swizzle,
// ONE barrier. K-loop: zero barriers, W depth-1 register prefetch from L2.
// ---------------------------------------------------------------------------
__global__ __launch_bounds__(256, 4) void gemm_kernel(const float* __restrict__ X,
                                                      const bf16_t* __restrict__ Wt,
                                                      float* __restrict__ out) {
    __shared__ __align__(16) bf16_t Xs[32 * 512];   // 32768 B

    const int t = threadIdx.x;
    const int w = t >> 6;
    const int l = t & 63;
    const int lc = l & 15;
    const int lr = l >> 4;
    const int m0 = blockIdx.x * 32;

    // W fragment pointers: wave w owns cols w*64 .. w*64+63
    const bf16_t* wp0 = Wt + (size_t)(w * 64 +  0 + lc) * KF + lr * 8;
    const bf16_t* wp1 = Wt + (size_t)(w * 64 + 16 + lc) * KF + lr * 8;
    const bf16_t* wp2 = Wt + (size_t)(w * 64 + 32 + lc) * KF + lr * 8;
    const bf16_t* wp3 = Wt + (size_t)(w * 64 + 48 + lc) * KF + lr * 8;

    bf16x8 wA[4], wB[4];
#define WLOAD(WREG, KS)                                        \
    WREG[0] = *(const bf16x8*)(wp0 + (KS) * 32);               \
    WREG[1] = *(const bf16x8*)(wp1 + (KS) * 32);               \
    WREG[2] = *(const bf16x8*)(wp2 + (KS) * 32);               \
    WREG[3] = *(const bf16x8*)(wp3 + (KS) * 32);

    WLOAD(wA, 0);   // overlaps staging

    // ---- staging: wave w stages rows w*8 .. w*8+7 (2KB contiguous burst
    // per row); logical 16B-chunk l stored at physical l ^ (r&7) (r&7 = sub)
    const float* Xbase = X + (size_t)m0 * KF;
#pragma unroll
    for (int sub = 0; sub < 8; ++sub) {
        const int r = w * 8 + sub;
        const float* rp = Xbase + (size_t)r * KF + l * 8;
        const float4 a = *(const float4*)rp;
        const float4 b = *(const float4*)(rp + 4);
        bf16x8 v;
        v[0] = (bf16_t)a.x; v[1] = (bf16_t)a.y;
        v[2] = (bf16_t)a.z; v[3] = (bf16_t)a.w;
        v[4] = (bf16_t)b.x; v[5] = (bf16_t)b.y;
        v[6] = (bf16_t)b.z; v[7] = (bf16_t)b.w;
        *(bf16x8*)&Xs[r * 512 + ((l ^ sub) * 8)] = v;
    }
    __syncthreads();   // the ONLY barrier

    f32x4 acc[2][4];
#pragma unroll
    for (int i = 0; i < 2; ++i)
#pragma unroll
        for (int j = 0; j < 4; ++j) acc[i][j] = (f32x4){0.f, 0.f, 0.f, 0.f};

    // A-frag: row mt*16+lc, logical chunk KS*4+lr, physical ^(lc&7)
#define GSTEP(KS, WREG)                                                        \
    {                                                                          \
        bf16x8 af[2];                                                          \
        _Pragma("unroll")                                                      \
        for (int mt = 0; mt < 2; ++mt) {                                       \
            const int row = mt * 16 + lc;                                      \
            const int ch = ((KS) * 4 + lr) ^ (lc & 7);                         \
            af[mt] = *(const bf16x8*)&Xs[row * 512 + ch * 8];                  \
        }                                                                      \
        _Pragma("unroll")                                                      \
        for (int mt = 0; mt < 2; ++mt)                                         \
            _Pragma("unroll")                                                  \
            for (int ntl = 0; ntl < 4; ++ntl)                                  \
                acc[mt][ntl] = __builtin_amdgcn_mfma_f32_16x16x32_bf16(        \
                    af[mt], WREG[ntl], acc[mt][ntl], 0, 0, 0);                 \
    }

#pragma unroll
    for (int kp = 0; kp < 8; ++kp) {
        const int ks0 = kp * 2;
        const int ks1 = kp * 2 + 1;
        WLOAD(wB, ks1);
        GSTEP(ks0, wA);
        if (ks1 < 15) { WLOAD(wA, ks1 + 1); }
        GSTEP(ks1, wB);
    }
#undef GSTEP
#undef WLOAD

    // ---- epilogue: row = m0 + mt*16 + lr*4 + j, col = w*64 + ntl*16 + lc ----
#pragma unroll
    for (int mt = 0; mt < 2; ++mt) {
#pragma unroll
        for (int ntl = 0; ntl < 4; ++ntl) {
            const int col = w * 64 + ntl * 16 + lc;
#pragma unroll
            for (int j = 0; j < 4; ++j) {
                const int row = m0 + mt * 16 + lr * 4 + j;
                out[(size_t)row * 512 + 256 + col] = acc[mt][ntl][j];
            }
        }
    }
}

// ---------------------------------------------------------------------------
// Kernel 2: per-batch attention (EXACT round-8 body, passing).
// ---------------------------------------------------------------------------
__global__ __launch_bounds__(256) void pv_kernel(const int* __restrict__ Adj,
                                                 const float* __restrict__ avec,
                                                 float* __restrict__ out) {
    __shared__ __align__(16) bf16_t hT[256 * HSTR];
    __shared__ __align__(16) bf16_t alp[80 * ASTR];
    __shared__ float a0s[F1], a1s[F1];
    __shared__ float attp0[4][80], attp1[4][80];
    __shared__ float att0s[80], att1s[80], rsums[80];
    __shared__ u64 adjb[160];

    const int b = blockIdx.x;
    const int t = threadIdx.x;
    const int w = t >> 6;
    const int l = t & 63;
    const int lc = l & 15;
    const int lr = l >> 4;
    float* outb = out + (size_t)b * NN * 512;

    a0s[t] = avec[t];
    a1s[t] = avec[F1 + t];
    for (int i = w; i < NN; i += 4) {
        const int v0 = Adj[i * NN + l];
        const int v1 = (l < NN - 64) ? Adj[i * NN + 64 + l] : 0;
        const u64 b0 = __ballot(v0 != 0);
        const u64 b1 = __ballot(v1 != 0);
        if (l == 0) { adjb[i * 2] = b0; adjb[i * 2 + 1] = b1; }
    }
    {
        int* z = (int*)&hT[t * HSTR + 80];
#pragma unroll
        for (int k = 0; k < 8; ++k) z[k] = 0;
    }
    __syncthreads();

    const int c0 = w * 64 + lc * 4;
    const float4 a04 = *(const float4*)&a0s[c0];
    const float4 a14 = *(const float4*)&a1s[c0];
#pragma unroll
    for (int jp = 0; jp < 5; ++jp) {
        const int j0 = jp * 16 + lr * 4;
        float hr[4][4];
#pragma unroll
        for (int r = 0; r < 4; ++r) {
            if (j0 + r < NN) {
                const float4 v = *(const float4*)(outb + (size_t)(j0 + r) * 512 + 256 + c0);
                hr[r][0] = v.x; hr[r][1] = v.y; hr[r][2] = v.z; hr[r][3] = v.w;
            } else {
                hr[r][0] = hr[r][1] = hr[r][2] = hr[r][3] = 0.f;
            }
        }
        float p0[4], p1[4];
#pragma unroll
        for (int r = 0; r < 4; ++r) {
            p0[r] = hr[r][0] * a04.x + hr[r][1] * a04.y + hr[r][2] * a04.z + hr[r][3] * a04.w;
            p1[r] = hr[r][0] * a14.x + hr[r][1] * a14.y + hr[r][2] * a14.z + hr[r][3] * a14.w;
        }
#pragma unroll
        for (int off = 1; off < 16; off <<= 1) {
#pragma unroll
            for (int r = 0; r < 4; ++r) {
                p0[r] += __shfl_xor(p0[r], off);
                p1[r] += __shfl_xor(p1[r], off);
            }
        }
        if (lc == 0) {
#pragma unroll
            for (int r = 0; r < 4; ++r) {
                attp0[w][j0 + r] = p0[r];
                attp1[w][j0 + r] = p1[r];
            }
        }
#pragma unroll
        for (int cc = 0; cc < 4; ++cc) {
            bf16x4_t v;
            v[0] = (bf16_t)hr[0][cc]; v[1] = (bf16_t)hr[1][cc];
            v[2] = (bf16_t)hr[2][cc]; v[3] = (bf16_t)hr[3][cc];
            *(bf16x4_t*)&hT[(c0 + cc) * HSTR + j0] = v;
        }
    }
    __syncthreads();

    if (t < 80)
        att0s[t] = attp0[0][t] + attp0[1][t] + attp0[2][t] + attp0[3][t];
    else if (t < 160)
        att1s[t - 80] = attp1[0][t - 80] + attp1[1][t - 80] + attp1[2][t - 80] + attp1[3][t - 80];
    else if (t < 240) {
        const int r = t - 160;
        if (r < NN) {
            for (int c = NN; c < 96; ++c) alp[r * ASTR + c] = (bf16_t)0.f;
        } else {
            for (int c = 0; c < 96; ++c) alp[r * ASTR + c] = (bf16_t)0.f;
        }
    }
    __syncthreads();

    {
        const int gid = t >> 2;
        const int k4 = t & 3;
#pragma unroll
        for (int r = 0; r < 2; ++r) {
            const int i = r * 64 + gid;
            if (i < NN) {
                const float a0i = att0s[i];
                const u64 w0 = adjb[i * 2];
                const u64 w1 = adjb[i * 2 + 1];
                float e[19];
                float m = -3.0e38f;
#pragma unroll
                for (int jj = 0; jj < 19; ++jj) {
                    const int j = jj * 4 + k4;
                    float ev = -3.0e38f;
                    if (j < NN) {
                        float x = a0i + att1s[j];
                        x = x > 0.f ? x : 0.2f * x;
                        const u64 wj = (j < 64) ? w0 : w1;
                        const int bit = (int)((wj >> (j & 63)) & 1);
                        ev = bit ? x : x - 1.0e9f;
                    }
                    e[jj] = ev;
                    m = fmaxf(m, ev);
                }
                m = fmaxf(m, __shfl_xor(m, 1));
                m = fmaxf(m, __shfl_xor(m, 2));
                float s = 0.f;
#pragma unroll
                for (int jj = 0; jj < 19; ++jj) {
                    const int j = jj * 4 + k4;
                    if (j < NN) {
                        const float ex = __expf(e[jj] - m);
                        s += ex;
                        alp[i * ASTR + j] = (bf16_t)ex;
                    }
                }
                s += __shfl_xor(s, 1);
                s += __shfl_xor(s, 2);
                if (k4 == 0) rsums[i] = 1.f / s;
            }
        }
    }
    __syncthreads();

    f32x4 acc2[5][4];
#pragma unroll
    for (int i = 0; i < 5; ++i)
#pragma unroll
        for (int j = 0; j < 4; ++j) acc2[i][j] = (f32x4){0.f, 0.f, 0.f, 0.f};

#pragma unroll
    for (int ks = 0; ks < 3; ++ks) {
        bf16x8 bv[4];
#pragma unroll
        for (int ntl = 0; ntl < 4; ++ntl) {
            const bf16_t* q = &hT[(w * 64 + ntl * 16 + lc) * HSTR + ks * 32 + lr * 8];
            ((uint2*)&bv[ntl])[0] = *(const uint2*)q;
            ((uint2*)&bv[ntl])[1] = *(const uint2*)(q + 4);
        }
#pragma unroll
        for (int mt = 0; mt < 5; ++mt) {
            const bf16_t* ap = &alp[(mt * 16 + lc) * ASTR + ks * 32 + lr * 8];
            bf16x8 av;
            ((uint2*)&av)[0] = *(const uint2*)ap;
            ((uint2*)&av)[1] = *(const uint2*)(ap + 4);
#pragma unroll
            for (int ntl = 0; ntl < 4; ++ntl)
                acc2[mt][ntl] = __builtin_amdgcn_mfma_f32_16x16x32_bf16(av, bv[ntl], acc2[mt][ntl], 0, 0, 0);
        }
    }

#pragma unroll
    for (int mt = 0; mt < 5; ++mt) {
#pragma unroll
        for (int j = 0; j < 4; ++j) {
            const int row = mt * 16 + lr * 4 + j;
            if (row < NN) {
                const float rsv = rsums[row];
#pragma unroll
                for (int ntl = 0; ntl < 4; ++ntl) {
                    const int ch = w * 64 + ntl * 16 + lc;
                    outb[(size_t)row * 512 + ch] = acc2[mt][ntl][j] * rsv;
                }
            }
        }
    }
}

// ---------------------------------------------------------------------------
extern "C" void kernel_launch(void* const* d_in, const int* in_sizes, int n_in,
                              void* d_out, int out_size, void* d_ws, size_t ws_size,
                              hipStream_t stream) {
    const float* X = (const float*)d_in[0];   // [1024,75,512] f32
    const int*   A = (const int*)d_in[1];     // [75,75] i32
    const float* W = (const float*)d_in[2];   // [512,256] f32
    const float* a = (const float*)d_in[3];   // [2,256,1] f32
    float* out = (float*)d_out;               // [1024,75,512] f32
    bf16_t* Wt = (bf16_t*)d_ws;               // 256 KB scratch

    wt_kernel<<<dim3(KF / 64, F1 / 64), 256, 0, stream>>>(W, Wt);
    gemm_kernel<<<(NB * NN) / 32, 256, 0, stream>>>(X, Wt, out);
    pv_kernel<<<NB, 256, 0, stream>>>(A, a, out);
}

// Round 20
// 124.991 us; speedup vs baseline: 1.3012x; 1.3012x over previous
//
#include <hip/hip_runtime.h>
#include <hip/hip_bf16.h>
#include <math.h>

typedef __bf16 bf16_t;
typedef __bf16 bf16x4_t __attribute__((ext_vector_type(4)));
typedef __bf16 bf16x8 __attribute__((ext_vector_type(8)));
typedef float f32x4 __attribute__((ext_vector_type(4)));
typedef unsigned long long u64;

typedef __attribute__((address_space(1))) const unsigned int cu32_g;
typedef __attribute__((address_space(3))) unsigned int u32_s;

#define NB 1024
#define NN 75
#define KF 512
#define F1 256
#define HSTR 100
#define ASTR 100
#define NT 1200     // gemm tiles (BM=64)
#define GRID 512    // persistent gemm blocks

// ---------------------------------------------------------------------------
// Kernel 0: W [512][256] fp32 -> Wt [256][512] bf16 (unchanged, passing)
// ---------------------------------------------------------------------------
__global__ __launch_bounds__(256) void wt_kernel(const float* __restrict__ W,
                                                 bf16_t* __restrict__ Wt) {
    __shared__ float tile[64][65];
    const int kb = blockIdx.x * 64;
    const int nb = blockIdx.y * 64;
    const int tc = threadIdx.x & 63;
    const int tr = threadIdx.x >> 6;
#pragma unroll
    for (int r = tr; r < 64; r += 4)
        tile[r][tc] = W[(size_t)(kb + r) * F1 + nb + tc];
    __syncthreads();
#pragma unroll
    for (int r = tr; r < 64; r += 4)
        Wt[(size_t)(nb + r) * KF + kb + tc] = (bf16_t)tile[tc][r];
}

// ---------------------------------------------------------------------------
// Kernel 1: h = X @ W -> out[...,256:512].  TILE-STREAMED DMA PIPELINE.
// 512 persistent blocks x 2-3 tiles. Per chunk (64 rows x 128 k fp32, 32KB):
//   issue 8 global_load_lds (next chunk -> other buf)   [DMA in flight...]
//   compute 4 K-steps from current buf (cvt fp32->bf16 at read, XOR swizzle)
//   asm vmcnt(0); raw s_barrier                         [...through compute]
// Loads are in flight during ~all wall time. W via r10 register dbuf (L2).
// ---------------------------------------------------------------------------
__global__ __launch_bounds__(256, 2) void gemm_kernel(const float* __restrict__ X,
                                                      const bf16_t* __restrict__ Wt,
                                                      float* __restrict__ out) {
    __shared__ __align__(16) float Xs[2][64 * 128];   // 2 x 32 KB

    const int t = threadIdx.x;
    const int w = t >> 6;
    const int l = t & 63;
    const int lc = l & 15;
    const int lr = l >> 4;

    // W fragment pointers (wave w owns cols w*64 .. w*64+63) — r10 proven
    const bf16_t* wp0 = Wt + (size_t)(w * 64 +  0 + lc) * KF + lr * 8;
    const bf16_t* wp1 = Wt + (size_t)(w * 64 + 16 + lc) * KF + lr * 8;
    const bf16_t* wp2 = Wt + (size_t)(w * 64 + 32 + lc) * KF + lr * 8;
    const bf16_t* wp3 = Wt + (size_t)(w * 64 + 48 + lc) * KF + lr * 8;
    bf16x8 wA[4], wB[4];
#define WLOAD(WREG, KS)                                        \
    WREG[0] = *(const bf16x8*)(wp0 + (KS) * 32);               \
    WREG[1] = *(const bf16x8*)(wp1 + (KS) * 32);               \
    WREG[2] = *(const bf16x8*)(wp2 + (KS) * 32);               \
    WREG[3] = *(const bf16x8*)(wp3 + (KS) * 32);

    // DMA staging: instr u (0..7): lane l -> row u*8 + w*2 + (l>>5),
    // physical 16B-slot l&31 holds logical chunk (l&31)^(row&7) (rule #21:
    // linear LDS dest, inverse-swizzled SOURCE, swizzled read).
    const int sl31 = l & 31;
#define ISSUE(BUF, TILE, C)                                                    \
    {                                                                          \
        _Pragma("unroll")                                                      \
        for (int u = 0; u < 8; ++u) {                                          \
            const int rowl = u * 8 + w * 2 + (l >> 5);                         \
            const float* g = X + ((size_t)(TILE) * 64 + rowl) * KF             \
                              + (C) * 128 + ((sl31 ^ (rowl & 7)) << 2);        \
            float* lp = &Xs[BUF][(u * 8 + w * 2) * 128];                       \
            __builtin_amdgcn_global_load_lds((cu32_g*)g, (u32_s*)lp, 16, 0, 0);\
        }                                                                      \
    }

    f32x4 acc[4][4];

    // compute one K-step: row mt*16+lc, logical slot s0=(KS&3)*8+lr*2,
    // physical = logical ^ (lc&7)
#define GSTEP(BUF, KS, WREG)                                                   \
    {                                                                          \
        bf16x8 af[4];                                                          \
        _Pragma("unroll")                                                      \
        for (int mt = 0; mt < 4; ++mt) {                                       \
            const int row = mt * 16 + lc;                                      \
            const int s0 = ((KS) & 3) * 8 + lr * 2;                            \
            const f32x4 fa = *(const f32x4*)&Xs[BUF][row * 128 +               \
                                                 ((s0 ^ (lc & 7)) << 2)];      \
            const f32x4 fb = *(const f32x4*)&Xs[BUF][row * 128 +               \
                                                 (((s0 + 1) ^ (lc & 7)) << 2)];\
            af[mt][0] = (bf16_t)fa[0]; af[mt][1] = (bf16_t)fa[1];              \
            af[mt][2] = (bf16_t)fa[2]; af[mt][3] = (bf16_t)fa[3];              \
            af[mt][4] = (bf16_t)fb[0]; af[mt][5] = (bf16_t)fb[1];              \
            af[mt][6] = (bf16_t)fb[2]; af[mt][7] = (bf16_t)fb[3];              \
        }                                                                      \
        _Pragma("unroll")                                                      \
        for (int mt = 0; mt < 4; ++mt)                                         \
            _Pragma("unroll")                                                  \
            for (int ntl = 0; ntl < 4; ++ntl)                                  \
                acc[mt][ntl] = __builtin_amdgcn_mfma_f32_16x16x32_bf16(        \
                    af[mt], WREG[ntl], acc[mt][ntl], 0, 0, 0);                 \
    }

#define FENCE_SWAP()                                                           \
    asm volatile("s_waitcnt vmcnt(0)" ::: "memory");                           \
    __builtin_amdgcn_s_barrier();                                              \
    __builtin_amdgcn_sched_barrier(0);

    // chunk body: C = 0..3 (compile-time), cur buf = C&1
#define CHUNK(C, TILE)                                                         \
    {                                                                          \
        if ((C) < 3) {                                                         \
            ISSUE(((C) + 1) & 1, TILE, (C) + 1);                               \
        } else if ((TILE) + GRID < NT) {                                       \
            ISSUE(0, (TILE) + GRID, 0);                                        \
        }                                                                      \
        __builtin_amdgcn_sched_barrier(0);                                     \
        WLOAD(wB, (C) * 4 + 1);                                                \
        GSTEP((C) & 1, (C) * 4 + 0, wA);                                       \
        WLOAD(wA, (C) * 4 + 2);                                                \
        GSTEP((C) & 1, (C) * 4 + 1, wB);                                       \
        WLOAD(wB, (C) * 4 + 3);                                                \
        GSTEP((C) & 1, (C) * 4 + 2, wA);                                       \
        WLOAD(wA, ((C) * 4 + 4) & 15);                                         \
        GSTEP((C) & 1, (C) * 4 + 3, wB);                                       \
        FENCE_SWAP();                                                          \
    }

    // ---- prologue ----
    WLOAD(wA, 0);
    int tile = blockIdx.x;
    ISSUE(0, tile, 0);
    FENCE_SWAP();

    // ---- persistent tile loop ----
    while (tile < NT) {
#pragma unroll
        for (int i = 0; i < 4; ++i)
#pragma unroll
            for (int j = 0; j < 4; ++j) acc[i][j] = (f32x4){0.f, 0.f, 0.f, 0.f};

        CHUNK(0, tile);
        CHUNK(1, tile);
        CHUNK(2, tile);
        CHUNK(3, tile);

        // epilogue: D row = mt*16 + lr*4 + j, col = w*64 + ntl*16 + lc
        const int m0 = tile * 64;
#pragma unroll
        for (int mt = 0; mt < 4; ++mt) {
#pragma unroll
            for (int ntl = 0; ntl < 4; ++ntl) {
                const int col = w * 64 + ntl * 16 + lc;
#pragma unroll
                for (int j = 0; j < 4; ++j) {
                    const int row = m0 + mt * 16 + lr * 4 + j;
                    out[(size_t)row * 512 + 256 + col] = acc[mt][ntl][j];
                }
            }
        }
        tile += GRID;
    }
#undef CHUNK
#undef FENCE_SWAP
#undef GSTEP
#undef ISSUE
#undef WLOAD
}

// ---------------------------------------------------------------------------
// Kernel 2: per-batch attention (EXACT round-8 body, passing).
// ---------------------------------------------------------------------------
__global__ __launch_bounds__(256) void pv_kernel(const int* __restrict__ Adj,
                                                 const float* __restrict__ avec,
                                                 float* __restrict__ out) {
    __shared__ __align__(16) bf16_t hT[256 * HSTR];
    __shared__ __align__(16) bf16_t alp[80 * ASTR];
    __shared__ float a0s[F1], a1s[F1];
    __shared__ float attp0[4][80], attp1[4][80];
    __shared__ float att0s[80], att1s[80], rsums[80];
    __shared__ u64 adjb[160];

    const int b = blockIdx.x;
    const int t = threadIdx.x;
    const int w = t >> 6;
    const int l = t & 63;
    const int lc = l & 15;
    const int lr = l >> 4;
    float* outb = out + (size_t)b * NN * 512;

    a0s[t] = avec[t];
    a1s[t] = avec[F1 + t];
    for (int i = w; i < NN; i += 4) {
        const int v0 = Adj[i * NN + l];
        const int v1 = (l < NN - 64) ? Adj[i * NN + 64 + l] : 0;
        const u64 b0 = __ballot(v0 != 0);
        const u64 b1 = __ballot(v1 != 0);
        if (l == 0) { adjb[i * 2] = b0; adjb[i * 2 + 1] = b1; }
    }
    {
        int* z = (int*)&hT[t * HSTR + 80];
#pragma unroll
        for (int k = 0; k < 8; ++k) z[k] = 0;
    }
    __syncthreads();

    const int c0 = w * 64 + lc * 4;
    const float4 a04 = *(const float4*)&a0s[c0];
    const float4 a14 = *(const float4*)&a1s[c0];
#pragma unroll
    for (int jp = 0; jp < 5; ++jp) {
        const int j0 = jp * 16 + lr * 4;
        float hr[4][4];
#pragma unroll
        for (int r = 0; r < 4; ++r) {
            if (j0 + r < NN) {
                const float4 v = *(const float4*)(outb + (size_t)(j0 + r) * 512 + 256 + c0);
                hr[r][0] = v.x; hr[r][1] = v.y; hr[r][2] = v.z; hr[r][3] = v.w;
            } else {
                hr[r][0] = hr[r][1] = hr[r][2] = hr[r][3] = 0.f;
            }
        }
        float p0[4], p1[4];
#pragma unroll
        for (int r = 0; r < 4; ++r) {
            p0[r] = hr[r][0] * a04.x + hr[r][1] * a04.y + hr[r][2] * a04.z + hr[r][3] * a04.w;
            p1[r] = hr[r][0] * a14.x + hr[r][1] * a14.y + hr[r][2] * a14.z + hr[r][3] * a14.w;
        }
#pragma unroll
        for (int off = 1; off < 16; off <<= 1) {
#pragma unroll
            for (int r = 0; r < 4; ++r) {
                p0[r] += __shfl_xor(p0[r], off);
                p1[r] += __shfl_xor(p1[r], off);
            }
        }
        if (lc == 0) {
#pragma unroll
            for (int r = 0; r < 4; ++r) {
                attp0[w][j0 + r] = p0[r];
                attp1[w][j0 + r] = p1[r];
            }
        }
#pragma unroll
        for (int cc = 0; cc < 4; ++cc) {
            bf16x4_t v;
            v[0] = (bf16_t)hr[0][cc]; v[1] = (bf16_t)hr[1][cc];
            v[2] = (bf16_t)hr[2][cc]; v[3] = (bf16_t)hr[3][cc];
            *(bf16x4_t*)&hT[(c0 + cc) * HSTR + j0] = v;
        }
    }
    __syncthreads();

    if (t < 80)
        att0s[t] = attp0[0][t] + attp0[1][t] + attp0[2][t] + attp0[3][t];
    else if (t < 160)
        att1s[t - 80] = attp1[0][t - 80] + attp1[1][t - 80] + attp1[2][t - 80] + attp1[3][t - 80];
    else if (t < 240) {
        const int r = t - 160;
        if (r < NN) {
            for (int c = NN; c < 96; ++c) alp[r * ASTR + c] = (bf16_t)0.f;
        } else {
            for (int c = 0; c < 96; ++c) alp[r * ASTR + c] = (bf16_t)0.f;
        }
    }
    __syncthreads();

    {
        const int gid = t >> 2;
        const int k4 = t & 3;
#pragma unroll
        for (int r = 0; r < 2; ++r) {
            const int i = r * 64 + gid;
            if (i < NN) {
                const float a0i = att0s[i];
                const u64 w0 = adjb[i * 2];
                const u64 w1 = adjb[i * 2 + 1];
                float e[19];
                float m = -3.0e38f;
#pragma unroll
                for (int jj = 0; jj < 19; ++jj) {
                    const int j = jj * 4 + k4;
                    float ev = -3.0e38f;
                    if (j < NN) {
                        float x = a0i + att1s[j];
                        x = x > 0.f ? x : 0.2f * x;
                        const u64 wj = (j < 64) ? w0 : w1;
                        const int bit = (int)((wj >> (j & 63)) & 1);
                        ev = bit ? x : x - 1.0e9f;
                    }
                    e[jj] = ev;
                    m = fmaxf(m, ev);
                }
                m = fmaxf(m, __shfl_xor(m, 1));
                m = fmaxf(m, __shfl_xor(m, 2));
                float s = 0.f;
#pragma unroll
                for (int jj = 0; jj < 19; ++jj) {
                    const int j = jj * 4 + k4;
                    if (j < NN) {
                        const float ex = __expf(e[jj] - m);
                        s += ex;
                        alp[i * ASTR + j] = (bf16_t)ex;
                    }
                }
                s += __shfl_xor(s, 1);
                s += __shfl_xor(s, 2);
                if (k4 == 0) rsums[i] = 1.f / s;
            }
        }
    }
    __syncthreads();

    f32x4 acc2[5][4];
#pragma unroll
    for (int i = 0; i < 5; ++i)
#pragma unroll
        for (int j = 0; j < 4; ++j) acc2[i][j] = (f32x4){0.f, 0.f, 0.f, 0.f};

#pragma unroll
    for (int ks = 0; ks < 3; ++ks) {
        bf16x8 bv[4];
#pragma unroll
        for (int ntl = 0; ntl < 4; ++ntl) {
            const bf16_t* q = &hT[(w * 64 + ntl * 16 + lc) * HSTR + ks * 32 + lr * 8];
            ((uint2*)&bv[ntl])[0] = *(const uint2*)q;
            ((uint2*)&bv[ntl])[1] = *(const uint2*)(q + 4);
        }
#pragma unroll
        for (int mt = 0; mt < 5; ++mt) {
            const bf16_t* ap = &alp[(mt * 16 + lc) * ASTR + ks * 32 + lr * 8];
            bf16x8 av;
            ((uint2*)&av)[0] = *(const uint2*)ap;
            ((uint2*)&av)[1] = *(const uint2*)(ap + 4);
#pragma unroll
            for (int ntl = 0; ntl < 4; ++ntl)
                acc2[mt][ntl] = __builtin_amdgcn_mfma_f32_16x16x32_bf16(av, bv[ntl], acc2[mt][ntl], 0, 0, 0);
        }
    }

#pragma unroll
    for (int mt = 0; mt < 5; ++mt) {
#pragma unroll
        for (int j = 0; j < 4; ++j) {
            const int row = mt * 16 + lr * 4 + j;
            if (row < NN) {
                const float rsv = rsums[row];
#pragma unroll
                for (int ntl = 0; ntl < 4; ++ntl) {
                    const int ch = w * 64 + ntl * 16 + lc;
                    outb[(size_t)row * 512 + ch] = acc2[mt][ntl][j] * rsv;
                }
            }
        }
    }
}

// ---------------------------------------------------------------------------
extern "C" void kernel_launch(void* const* d_in, const int* in_sizes, int n_in,
                              void* d_out, int out_size, void* d_ws, size_t ws_size,
                              hipStream_t stream) {
    const float* X = (const float*)d_in[0];   // [1024,75,512] f32
    const int*   A = (const int*)d_in[1];     // [75,75] i32
    const float* W = (const float*)d_in[2];   // [512,256] f32
    const float* a = (const float*)d_in[3];   // [2,256,1] f32
    float* out = (float*)d_out;               // [1024,75,512] f32
    bf16_t* Wt = (bf16_t*)d_ws;               // 256 KB scratch

    wt_kernel<<<dim3(KF / 64, F1 / 64), 256, 0, stream>>>(W, Wt);
    gemm_kernel<<<GRID, 256, 0, stream>>>(X, Wt, out);
    pv_kernel<<<NB, 256, 0, stream>>>(A, a, out);
}